// Round 21
// baseline (88.064 us; speedup 1.0000x reference)
//
#include <hip/hip_runtime.h>

#define BATCH 512
#define NC 3
#define TT 4096
#define HH 17
#define NBLK (TT / 4)     // float4 time-blocks per sequence
#define WU_BLKS 3         // 12 warm-up steps (rho^12~1.4e-3; invisible at r20)
#define NSEQ (BATCH * 2)
#define SCALE 2.8853900817779268f   // 2*log2(e), folded into weights/bias

typedef __attribute__((ext_vector_type(8))) short short8;
typedef __attribute__((ext_vector_type(16))) float f32x16;

union B8 { unsigned u[4]; short8 s; };

__device__ __forceinline__ float fast_exp2(float y) {
#if __has_builtin(__builtin_amdgcn_exp2f)
    return __builtin_amdgcn_exp2f(y);   // bare v_exp_f32
#else
    return exp2f(y);
#endif
}

// tanh with 2*log2(e) pre-folded into the MFMA weights:
// d = 2*log2e*(Wh+Ux+b)  ->  tanh = 1 - 2/(2^d + 1).
__device__ __forceinline__ float fast_tanh_pre(float d) {
    float e = fast_exp2(d);
    float r = __builtin_amdgcn_rcpf(e + 1.0f);
    return fmaf(-2.0f, r, 1.0f);
}

__device__ __forceinline__ unsigned cvt_pk_bf16(float lo, float hi) {
    unsigned r;  // r[15:0]=bf16(lo), r[31:16]=bf16(hi), RNE
    asm("v_cvt_pk_bf16_f32 %0, %1, %2" : "=v"(r) : "v"(lo), "v"(hi));
    return r;
}

__device__ __forceinline__ unsigned short bf16_rne(float f) {
    unsigned u = __float_as_uint(f);
    unsigned r = u + 0x7FFFu + ((u >> 16) & 1u);
    return (unsigned short)(r >> 16);
}

// x[B][C][T] -> prepacked bf16 B2-operand words, lane-contiguous in b.
__global__ __launch_bounds__(256) void transpose_kernel(
    const float4* __restrict__ x4, uint4* __restrict__ w12,
    uint4* __restrict__ w0) {
    __shared__ float4 tile[NC][32][33];
    int bid = blockIdx.x;
    int tb = bid & 15;          // batch tile (16)
    int tt = bid >> 4;          // t4 tile (32)
    int b0 = tb * 32, t40 = tt * 32;
    int jr = threadIdx.x & 31, pr = threadIdx.x >> 5;
#pragma unroll
    for (int c = 0; c < NC; ++c)
#pragma unroll
        for (int p = 0; p < 4; ++p) {
            int r = p * 8 + pr;
            tile[c][r][jr] =
                x4[(size_t)(b0 + r) * (NC * NBLK) + c * NBLK + t40 + jr];
        }
    __syncthreads();
#pragma unroll
    for (int p = 0; p < 4; ++p) {
        int j = p * 8 + pr;
        int b = jr;
        float4 c0 = tile[0][b][j];
        float4 c1 = tile[1][b][j];
        float4 c2 = tile[2][b][j];
        uint4 a, z;
        a.x = cvt_pk_bf16(c1.x, c2.x); z.x = cvt_pk_bf16(0.0f, c0.x);
        a.y = cvt_pk_bf16(c1.y, c2.y); z.y = cvt_pk_bf16(0.0f, c0.y);
        a.z = cvt_pk_bf16(c1.z, c2.z); z.z = cvt_pk_bf16(0.0f, c0.z);
        a.w = cvt_pk_bf16(c1.w, c2.w); z.w = cvt_pk_bf16(0.0f, c0.w);
        size_t idx = (size_t)(t40 + j) * BATCH + b0 + b;
        w12[idx] = a;
        w0[idx] = z;
    }
}

// TWO independent chunks (A, B) of the same sequence interleaved per step:
// chain A's MFMA/tanh latency is hidden under chain B's issue and vice versa
// (breaks the 4-wave lockstep bunching stall identified r13-r20).
// Per-chunk math is instruction-identical to r20's run_loop.
// The if(g) B2 masking is EMPIRICALLY REQUIRED (r8/r16 NaN) — keep.
template <int DIR>
__device__ __forceinline__ void run_pair(
    const uint4* __restrict__ p12, const uint4* __restrict__ p0,
    short8 Ahi, short8 Alo, short8 A2hi, short8 A2lo,
    f32x16 Cb, int g, int blkMainA, int blkMainB, int bpc,
    float* hsA, float* hsB) {

    short8 BhiA = {0,0,0,0,0,0,0,0};
    short8 BhiB = {0,0,0,0,0,0,0,0};
    unsigned h16bA = 0, h16bB = 0;

    const int T = WU_BLKS + bpc;
    int blkA = blkMainA - WU_BLKS;   // may be negative for chunk 0 (A idles)
    int blkB = blkMainB - WU_BLKS;   // always >= 0 (cB >= nchunk/2)
    const int endA = blkMainA + bpc - 1;
    const int endB = blkMainB + bpc - 1;

#define T4OF(blk) (DIR ? (NBLK - 1 - ((blk) < 0 ? 0 : (blk))) \
                       : ((blk) < 0 ? 0 : (blk)))
    int t4A = T4OF(blkA), t4B = T4OF(blkB);
    uint4 c12A = p12[(size_t)t4A * BATCH], c0A = p0[(size_t)t4A * BATCH];
    uint4 c12B = p12[(size_t)t4B * BATCH], c0B = p0[(size_t)t4B * BATCH];

    for (int i = 0; i < T; ++i) {
        int nA = (blkA + 1 > endA) ? endA : blkA + 1;   // clamped prefetch
        int nB = (blkB + 1 > endB) ? endB : blkB + 1;
        int t4An = T4OF(nA), t4Bn = T4OF(nB);
        uint4 n12A = p12[(size_t)t4An * BATCH], n0A = p0[(size_t)t4An * BATCH];
        uint4 n12B = p12[(size_t)t4Bn * BATCH], n0B = p0[(size_t)t4Bn * BATCH];

        const float flagA = (blkA >= blkMainA) ? 1.0f : 0.0f;
        const float flagB = (blkB >= blkMainB) ? 1.0f : 0.0f;
        const bool updA = (blkA >= 0);   // wave-uniform guard (chunk 0 warm-up)

        unsigned a12A[4] = {c12A.x, c12A.y, c12A.z, c12A.w};
        unsigned a0A[4] = {c0A.x, c0A.y, c0A.z, c0A.w};
        unsigned a12B[4] = {c12B.x, c12B.y, c12B.z, c12B.w};
        unsigned a0B[4] = {c0B.x, c0B.y, c0B.z, c0B.w};

#pragma unroll
        for (int k = 0; k < 4; ++k) {
            const int kk = DIR ? (3 - k) : k;

            unsigned t0A = h16bA | a0A[kk];
            unsigned t1A = a12A[kk];
            unsigned t0B = h16bB | a0B[kk];
            unsigned t1B = a12B[kk];
            if (g) { t0A = 0; t1A = 0; t0B = 0; t1B = 0; }
            B8 thA; thA.u[0] = t0A; thA.u[1] = t1A; thA.u[2] = 0; thA.u[3] = 0;
            B8 thB; thB.u[0] = t0B; thB.u[1] = t1B; thB.u[2] = 0; thB.u[3] = 0;

            // two independent 4-deep chains, interleaved
            f32x16 DA = __builtin_amdgcn_mfma_f32_32x32x16_bf16(Ahi, BhiA, Cb, 0, 0, 0);
            f32x16 DB = __builtin_amdgcn_mfma_f32_32x32x16_bf16(Ahi, BhiB, Cb, 0, 0, 0);
            DA = __builtin_amdgcn_mfma_f32_32x32x16_bf16(Alo, BhiA, DA, 0, 0, 0);
            DB = __builtin_amdgcn_mfma_f32_32x32x16_bf16(Alo, BhiB, DB, 0, 0, 0);
            DA = __builtin_amdgcn_mfma_f32_32x32x16_bf16(A2hi, thA.s, DA, 0, 0, 0);
            DB = __builtin_amdgcn_mfma_f32_32x32x16_bf16(A2hi, thB.s, DB, 0, 0, 0);
            DA = __builtin_amdgcn_mfma_f32_32x32x16_bf16(A2lo, thA.s, DA, 0, 0, 0);
            DB = __builtin_amdgcn_mfma_f32_32x32x16_bf16(A2lo, thB.s, DB, 0, 0, 0);

            float htA[9], htB[9];
#pragma unroll
            for (int r = 0; r < 9; ++r) {
                htA[r] = fast_tanh_pre(DA[r]);
                htB[r] = fast_tanh_pre(DB[r]);
                hsA[r] = fmaf(htA[r], flagA, hsA[r]);
                hsB[r] = fmaf(htB[r], flagB, hsB[r]);
            }
            B8 nhA, nhB;
            nhA.u[0] = cvt_pk_bf16(htA[0], htA[1]);
            nhB.u[0] = cvt_pk_bf16(htB[0], htB[1]);
            nhA.u[1] = cvt_pk_bf16(htA[2], htA[3]);
            nhB.u[1] = cvt_pk_bf16(htB[2], htB[3]);
            nhA.u[2] = cvt_pk_bf16(htA[4], htA[5]);
            nhB.u[2] = cvt_pk_bf16(htB[4], htB[5]);
            nhA.u[3] = cvt_pk_bf16(htA[6], htA[7]);
            nhB.u[3] = cvt_pk_bf16(htB[6], htB[7]);
            if (updA) {
                BhiA = nhA.s;
                h16bA = cvt_pk_bf16(htA[8], 0.0f);
            }
            BhiB = nhB.s;
            h16bB = cvt_pk_bf16(htB[8], 0.0f);
        }
        blkA += 1; blkB += 1;
        c12A = n12A; c0A = n0A;
        c12B = n12B; c0B = n0B;
    }
#undef T4OF
}

// 4 independent waves per 256-thread block; each wave owns chunk pair
// (p, p + nchunk/2) of one (batch-group, dir) sequence set.
__global__ __launch_bounds__(256) void rnn_kernel(
    const uint4* __restrict__ w12, const uint4* __restrict__ w0,
    const float* __restrict__ W_ih_f, const float* __restrict__ W_hh_f,
    const float* __restrict__ b_ih_f, const float* __restrict__ b_hh_f,
    const float* __restrict__ W_ih_b, const float* __restrict__ W_hh_b,
    const float* __restrict__ b_ih_b, const float* __restrict__ b_hh_b,
    float* __restrict__ partial, int nchunk, int bpc) {
    int wv = threadIdx.x >> 6;          // wave within block
    int wid = blockIdx.x * 4 + wv;      // (nchunk/2)%4==0 -> same q per block
    int half = nchunk >> 1;
    int p = wid % half;                 // chunk-pair id
    int q = wid / half;
    int cA = p, cB = p + half;
    int dir = q & 1;
    int grp = q >> 1;            // 0..15 (batch groups of 32)
    int lane = threadIdx.x & 63;
    int n = lane & 31;           // column = batch within group
    int g = lane >> 5;           // k-block / row-block selector
    int m = n;                   // A-operand row owned by this lane
    int bn = grp * 32 + n;

    const float* W_ih = dir ? W_ih_b : W_ih_f;
    const float* W_hh = dir ? W_hh_b : W_hh_f;
    const float* b_ih = dir ? b_ih_b : b_ih_f;
    const float* b_hh = dir ? b_hh_b : b_hh_f;

    // A fragment: rows m (pad >=17 with 0), k-slots {4g+i, 8+4g+i}
    // Weights pre-scaled by 2*log2e, hi/lo split AFTER scaling.
    short8 Ahi, Alo, A2hi, A2lo;
#pragma unroll
    for (int i = 0; i < 8; ++i) {
        int k = (i < 4) ? (4 * g + i) : (8 + 4 * g + (i - 4));
        float wv_ = (m < HH && k < HH) ? W_hh[m * HH + k] * SCALE : 0.0f;
        unsigned short hb = bf16_rne(wv_);
        float hf = __uint_as_float(((unsigned)hb) << 16);
        Ahi[i] = (short)hb;
        Alo[i] = (short)bf16_rne(wv_ - hf);
        // A2: k2-slots {16+4g+i, 24+4g+i}: k2==16 -> W_hh[:,16]; 17..19 -> W_ih
        int k2 = (i < 4) ? (16 + 4 * g + i) : (24 + 4 * g + (i - 4));
        float wv2 = 0.0f;
        if (m < HH) {
            if (k2 == 16) wv2 = W_hh[m * HH + 16] * SCALE;
            else if (k2 >= 17 && k2 <= 19) wv2 = W_ih[m * NC + (k2 - 17)] * SCALE;
        }
        unsigned short hb2 = bf16_rne(wv2);
        float hf2 = __uint_as_float(((unsigned)hb2) << 16);
        A2hi[i] = (short)hb2;
        A2lo[i] = (short)bf16_rne(wv2 - hf2);
    }

    // C bias (pre-scaled): reg r holds row (r&3)+8*(r>>2)+4g; zero dead rows
    f32x16 Cb;
#pragma unroll
    for (int r = 0; r < 16; ++r) {
        int row = (r & 3) + 8 * (r >> 2) + 4 * g;
        Cb[r] = (row < HH) ? (b_ih[row] + b_hh[row]) * SCALE : 0.0f;
    }

    const uint4* p12 = w12 + bn;
    const uint4* p0 = w0 + bn;

    float hsA[9], hsB[9];
#pragma unroll
    for (int r = 0; r < 9; ++r) { hsA[r] = 0.0f; hsB[r] = 0.0f; }

    if (dir == 0)
        run_pair<0>(p12, p0, Ahi, Alo, A2hi, A2lo, Cb, g,
                    cA * bpc, cB * bpc, bpc, hsA, hsB);
    else
        run_pair<1>(p12, p0, Ahi, Alo, A2hi, A2lo, Cb, g,
                    cA * bpc, cB * bpc, bpc, hsA, hsB);

    // partial layout [chunk][seq][comp]: coalesced finalize reads
    int seq = bn * 2 + dir;
#pragma unroll
    for (int r = 0; r < 9; ++r) {
        int row = (r & 3) + 8 * (r >> 2) + 4 * g;
        if (row < HH) {
            partial[(size_t)cA * (NSEQ * HH) + seq * HH + row] = hsA[r];
            partial[(size_t)cB * (NSEQ * HH) + seq * HH + row] = hsB[r];
        }
    }
}

// Fused reduce+conv: one 64-thread block per batch (r19-proven).
__global__ __launch_bounds__(64) void finalize_kernel(
    const float* __restrict__ partial, const float* __restrict__ conv_w,
    const float* __restrict__ conv_b, float* __restrict__ out, int nchunk) {
    int b = blockIdx.x;
    int lane = threadIdx.x;
    float tot = 0.0f;
    if (lane < 2 * HH) {
        const float* p = partial + (size_t)b * (2 * HH) + lane;
        float s0 = 0.0f, s1 = 0.0f, s2 = 0.0f, s3 = 0.0f;
        int c = 0;
        for (; c + 4 <= nchunk; c += 4) {
            s0 += p[(size_t)(c + 0) * (NSEQ * HH)];
            s1 += p[(size_t)(c + 1) * (NSEQ * HH)];
            s2 += p[(size_t)(c + 2) * (NSEQ * HH)];
            s3 += p[(size_t)(c + 3) * (NSEQ * HH)];
        }
        for (; c < nchunk; ++c) s0 += p[(size_t)c * (NSEQ * HH)];
        tot = (s0 + s1) + (s2 + s3);
    }
    float c0 = 0.0f, c1 = 0.0f;
    if (lane < 2 * HH) {
        c0 = conv_w[lane] * tot;            // conv_w[0][concat]
        c1 = conv_w[2 * HH + lane] * tot;   // conv_w[1][concat]
    }
#pragma unroll
    for (int off = 32; off; off >>= 1) {
        c0 += __shfl_down(c0, off);
        c1 += __shfl_down(c1, off);
    }
    if (lane == 0) {
        const float inv = 1.0f / (float)TT;
        out[b * 2 + 0] = fmaf(c0, inv, conv_b[0]);
        out[b * 2 + 1] = fmaf(c1, inv, conv_b[1]);
    }
}

extern "C" void kernel_launch(void* const* d_in, const int* in_sizes, int n_in,
                              void* d_out, int out_size, void* d_ws, size_t ws_size,
                              hipStream_t stream) {
    const float* x      = (const float*)d_in[0];
    const float* W_ih_f = (const float*)d_in[1];
    const float* W_hh_f = (const float*)d_in[2];
    const float* b_ih_f = (const float*)d_in[3];
    const float* b_hh_f = (const float*)d_in[4];
    const float* W_ih_b = (const float*)d_in[5];
    const float* W_hh_b = (const float*)d_in[6];
    const float* b_ih_b = (const float*)d_in[7];
    const float* b_hh_b = (const float*)d_in[8];
    const float* conv_w = (const float*)d_in[9];
    const float* conv_b = (const float*)d_in[10];

    // ws layout: [w12 8.4MB][w0 8.4MB][partial]
    const size_t wbytes = (size_t)NBLK * BATCH * 16;  // uint4 per (t4,b)
    const size_t pbytes1 = (size_t)NSEQ * HH * 4;     // per chunk
    size_t pbase = 2 * wbytes;
    int nchunk = 256;   // bpc=4; waves carry 2 chunks each -> 4096 waves
    while (nchunk > 8 && ws_size < pbase + (size_t)nchunk * pbytes1)
        nchunk >>= 1;
    int bpc = NBLK / nchunk;

    uint4* w12 = (uint4*)d_ws;
    uint4* w0 = (uint4*)((char*)d_ws + wbytes);
    float* partial = (float*)((char*)d_ws + pbase);
    float* out = (float*)d_out;

    transpose_kernel<<<dim3(16 * 32), dim3(256), 0, stream>>>(
        (const float4*)x, w12, w0);
    // waves = 32 * nchunk/2; blocks = waves/4 = 4*nchunk
    rnn_kernel<<<dim3(4 * nchunk), dim3(256), 0, stream>>>(
        w12, w0, W_ih_f, W_hh_f, b_ih_f, b_hh_f,
        W_ih_b, W_hh_b, b_ih_b, b_hh_b, partial, nchunk, bpc);
    finalize_kernel<<<dim3(BATCH), dim3(64), 0, stream>>>(
        partial, conv_w, conv_b, out, nchunk);
}

// Round 22
// 60.130 us; speedup vs baseline: 1.4646x; 1.4646x over previous
//
#include <hip/hip_runtime.h>
#include <hip/hip_fp16.h>

#define BATCH 512
#define NC 3
#define TT 4096
#define HH 17
#define NBLK (TT / 4)     // float4 time-blocks per sequence
#define WU_BLKS 3         // 12 warm-up steps (rho^12~1.4e-3 -> ~7e-5 on out)
#define NSEQ (BATCH * 2)
#define SCALE 2.8853900817779268f   // 2*log2(e), folded into weights/bias

typedef __attribute__((ext_vector_type(8))) _Float16 half8;
typedef __attribute__((ext_vector_type(16))) float f32x16;

union H8 { unsigned u[4]; half8 s; };

__device__ __forceinline__ float fast_exp2(float y) {
#if __has_builtin(__builtin_amdgcn_exp2f)
    return __builtin_amdgcn_exp2f(y);   // bare v_exp_f32
#else
    return exp2f(y);
#endif
}

// tanh with 2*log2(e) pre-folded into the MFMA weights:
// d = 2*log2e*(Wh+Ux+b)  ->  tanh = 1 - 2/(2^d + 1).
__device__ __forceinline__ float fast_tanh_pre(float d) {
    float e = fast_exp2(d);
    float r = __builtin_amdgcn_rcpf(e + 1.0f);
    return fmaf(-2.0f, r, 1.0f);
}

// RNE fp16 helpers (v_cvt_f16_f32 default round mode; NOT pkrtz - RTZ would
// systematically shrink h toward zero through the recurrence).
__device__ __forceinline__ unsigned h16u(float f) {
    return (unsigned)__half_as_ushort(__float2half(f));
}
__device__ __forceinline__ unsigned pk2h(float lo, float hi) {
    return h16u(lo) | (h16u(hi) << 16);
}

// x[B][C][T] -> prepacked fp16 B2-operand words, lane-contiguous in b:
//   w12[t4*BATCH+b] = fp16(x1) | fp16(x2)<<16  (4 t's per block)
//   w0 [t4*BATCH+b] = fp16(x0)<<16
__global__ __launch_bounds__(256) void transpose_kernel(
    const float4* __restrict__ x4, uint4* __restrict__ w12,
    uint4* __restrict__ w0) {
    __shared__ float4 tile[NC][32][33];
    int bid = blockIdx.x;
    int tb = bid & 15;          // batch tile (16)
    int tt = bid >> 4;          // t4 tile (32)
    int b0 = tb * 32, t40 = tt * 32;
    int jr = threadIdx.x & 31, pr = threadIdx.x >> 5;
#pragma unroll
    for (int c = 0; c < NC; ++c)
#pragma unroll
        for (int p = 0; p < 4; ++p) {
            int r = p * 8 + pr;
            tile[c][r][jr] =
                x4[(size_t)(b0 + r) * (NC * NBLK) + c * NBLK + t40 + jr];
        }
    __syncthreads();
#pragma unroll
    for (int p = 0; p < 4; ++p) {
        int j = p * 8 + pr;
        int b = jr;
        float4 c0 = tile[0][b][j];
        float4 c1 = tile[1][b][j];
        float4 c2 = tile[2][b][j];
        uint4 a, z;
        a.x = pk2h(c1.x, c2.x); z.x = h16u(c0.x) << 16;
        a.y = pk2h(c1.y, c2.y); z.y = h16u(c0.y) << 16;
        a.z = pk2h(c1.z, c2.z); z.z = h16u(c0.z) << 16;
        a.w = pk2h(c1.w, c2.w); z.w = h16u(c0.w) << 16;
        size_t idx = (size_t)(t40 + j) * BATCH + b0 + b;
        w12[idx] = a;
        w0[idx] = z;
    }
}

// Recurrence over one chunk — fp16 single-precision weights (11-bit mantissa
// replaces the bf16 hi+lo split): TWO MFMAs per step instead of four.
// D = s*[W_hh | W_hh[:,16], W_ih] x [h ; h16, x_t] + s*bias.
// D regs 0..7 of a lane ARE its next-step B fragment k-slots.
// The if(g) B2 masking is EMPIRICALLY REQUIRED (r8/r16 NaN) — keep.
template <int DIR>
__device__ __forceinline__ void run_loop(
    const uint4* __restrict__ p12, const uint4* __restrict__ p0,
    half8 A1, half8 A2,
    f32x16 Cb, int g, int blk0, int blkMain, int blkEnd, float* hs) {

    half8 Bhi = {0,0,0,0,0,0,0,0};
    unsigned h16b = 0;  // [15:0]=fp16(h16), rest 0

    int t4 = DIR ? (NBLK - 1 - blk0) : blk0;
    uint4 c12 = p12[(size_t)t4 * BATCH];
    uint4 c0 = p0[(size_t)t4 * BATCH];
    const int dstep = DIR ? -1 : 1;

    for (int blk = blk0; blk < blkEnd; ++blk) {
        int nt4 = (blk + 1 < blkEnd) ? t4 + dstep : t4;  // clamped prefetch
        uint4 n12 = p12[(size_t)nt4 * BATCH];
        uint4 n0 = p0[(size_t)nt4 * BATCH];

        const float flag = (blk >= blkMain) ? 1.0f : 0.0f;  // warm-up mask
        unsigned a12[4] = {c12.x, c12.y, c12.z, c12.w};
        unsigned a0[4] = {c0.x, c0.y, c0.z, c0.w};

#pragma unroll
        for (int k = 0; k < 4; ++k) {
            const int kk = DIR ? (3 - k) : k;

            // B2 = [h16, x0, x1, x2] fp16 (g==0 lanes live; mask REQUIRED)
            unsigned t0 = h16b | a0[kk];   // [15:0]=fp16(h16) [31:16]=fp16(x0)
            unsigned t1 = a12[kk];         // [15:0]=fp16(x1)  [31:16]=fp16(x2)
            if (g) { t0 = 0; t1 = 0; }
            H8 th; th.u[0] = t0; th.u[1] = t1; th.u[2] = 0; th.u[3] = 0;

            // two-MFMA chain (fp16 weights, fp16 data, fp32 accumulate)
            f32x16 D = __builtin_amdgcn_mfma_f32_32x32x16_f16(A1, Bhi, Cb, 0, 0, 0);
            D = __builtin_amdgcn_mfma_f32_32x32x16_f16(A2, th.s, D, 0, 0, 0);

            // tanh on live regs (rows <17 live in regs 0..8), accumulate sums
            float ht[9];
#pragma unroll
            for (int r = 0; r < 9; ++r) {
                ht[r] = fast_tanh_pre(D[r]);
                hs[r] = fmaf(ht[r], flag, hs[r]);
            }
            // next-step B fragment: regs 0..7 are exactly this lane's k-slots
            H8 nh;
            nh.u[0] = pk2h(ht[0], ht[1]);
            nh.u[1] = pk2h(ht[2], ht[3]);
            nh.u[2] = pk2h(ht[4], ht[5]);
            nh.u[3] = pk2h(ht[6], ht[7]);
            Bhi = nh.s;
            h16b = h16u(ht[8]);  // [15:0]=fp16(h16)
        }
        t4 = nt4;
        c12 = n12; c0 = n0;
    }
}

// 4 independent waves per 256-thread block (r15-proven geometry).
__global__ __launch_bounds__(256) void rnn_kernel(
    const uint4* __restrict__ w12, const uint4* __restrict__ w0,
    const float* __restrict__ W_ih_f, const float* __restrict__ W_hh_f,
    const float* __restrict__ b_ih_f, const float* __restrict__ b_hh_f,
    const float* __restrict__ W_ih_b, const float* __restrict__ W_hh_b,
    const float* __restrict__ b_ih_b, const float* __restrict__ b_hh_b,
    float* __restrict__ partial, int nchunk, int bpc) {
    int wv = threadIdx.x >> 6;          // wave within block
    int wid = blockIdx.x * 4 + wv;      // global wave id (nchunk%4==0 -> same q)
    int chunk = wid % nchunk;
    int q = wid / nchunk;
    int dir = q & 1;
    int grp = q >> 1;            // 0..15 (batch groups of 32)
    int lane = threadIdx.x & 63;
    int n = lane & 31;           // column = batch within group
    int g = lane >> 5;           // k-block / row-block selector
    int m = n;                   // A-operand row owned by this lane
    int bn = grp * 32 + n;

    const float* W_ih = dir ? W_ih_b : W_ih_f;
    const float* W_hh = dir ? W_hh_b : W_hh_f;
    const float* b_ih = dir ? b_ih_b : b_ih_f;
    const float* b_hh = dir ? b_hh_b : b_hh_f;

    // A fragments (fp16, RNE): rows m (pad >=17 with 0), k-slots {4g+i, 8+4g+i}
    // Weights pre-scaled by 2*log2e.
    half8 A1, A2;
#pragma unroll
    for (int i = 0; i < 8; ++i) {
        int k = (i < 4) ? (4 * g + i) : (8 + 4 * g + (i - 4));
        float wv_ = (m < HH && k < HH) ? W_hh[m * HH + k] * SCALE : 0.0f;
        A1[i] = (_Float16)wv_;
        // A2: k2-slots {16+4g+i, 24+4g+i}: k2==16 -> W_hh[:,16]; 17..19 -> W_ih
        int k2 = (i < 4) ? (16 + 4 * g + i) : (24 + 4 * g + (i - 4));
        float wv2 = 0.0f;
        if (m < HH) {
            if (k2 == 16) wv2 = W_hh[m * HH + 16] * SCALE;
            else if (k2 >= 17 && k2 <= 19) wv2 = W_ih[m * NC + (k2 - 17)] * SCALE;
        }
        A2[i] = (_Float16)wv2;
    }

    // C bias (pre-scaled): reg r holds row (r&3)+8*(r>>2)+4g; zero dead rows
    f32x16 Cb;
#pragma unroll
    for (int r = 0; r < 16; ++r) {
        int row = (r & 3) + 8 * (r >> 2) + 4 * g;
        Cb[r] = (row < HH) ? (b_ih[row] + b_hh[row]) * SCALE : 0.0f;
    }

    int blkMain = chunk * bpc;
    int blk0 = chunk ? (blkMain - WU_BLKS) : 0;
    int blkEnd = blkMain + bpc;

    const uint4* p12 = w12 + bn;
    const uint4* p0 = w0 + bn;

    float hs[9];
#pragma unroll
    for (int r = 0; r < 9; ++r) hs[r] = 0.0f;

    if (dir == 0)
        run_loop<0>(p12, p0, A1, A2, Cb, g, blk0, blkMain, blkEnd, hs);
    else
        run_loop<1>(p12, p0, A1, A2, Cb, g, blk0, blkMain, blkEnd, hs);

    // partial layout [chunk][seq][comp]: coalesced finalize reads
    int seq = bn * 2 + dir;
#pragma unroll
    for (int r = 0; r < 9; ++r) {
        int row = (r & 3) + 8 * (r >> 2) + 4 * g;
        if (row < HH)
            partial[(size_t)chunk * (NSEQ * HH) + seq * HH + row] = hs[r];
    }
}

// Fused reduce+conv: one 64-thread block per batch (r19-proven).
__global__ __launch_bounds__(64) void finalize_kernel(
    const float* __restrict__ partial, const float* __restrict__ conv_w,
    const float* __restrict__ conv_b, float* __restrict__ out, int nchunk) {
    int b = blockIdx.x;
    int lane = threadIdx.x;
    float tot = 0.0f;
    if (lane < 2 * HH) {
        const float* p = partial + (size_t)b * (2 * HH) + lane;
        float s0 = 0.0f, s1 = 0.0f, s2 = 0.0f, s3 = 0.0f;
        int c = 0;
        for (; c + 4 <= nchunk; c += 4) {
            s0 += p[(size_t)(c + 0) * (NSEQ * HH)];
            s1 += p[(size_t)(c + 1) * (NSEQ * HH)];
            s2 += p[(size_t)(c + 2) * (NSEQ * HH)];
            s3 += p[(size_t)(c + 3) * (NSEQ * HH)];
        }
        for (; c < nchunk; ++c) s0 += p[(size_t)c * (NSEQ * HH)];
        tot = (s0 + s1) + (s2 + s3);
    }
    float c0 = 0.0f, c1 = 0.0f;
    if (lane < 2 * HH) {
        c0 = conv_w[lane] * tot;            // conv_w[0][concat]
        c1 = conv_w[2 * HH + lane] * tot;   // conv_w[1][concat]
    }
#pragma unroll
    for (int off = 32; off; off >>= 1) {
        c0 += __shfl_down(c0, off);
        c1 += __shfl_down(c1, off);
    }
    if (lane == 0) {
        const float inv = 1.0f / (float)TT;
        out[b * 2 + 0] = fmaf(c0, inv, conv_b[0]);
        out[b * 2 + 1] = fmaf(c1, inv, conv_b[1]);
    }
}

extern "C" void kernel_launch(void* const* d_in, const int* in_sizes, int n_in,
                              void* d_out, int out_size, void* d_ws, size_t ws_size,
                              hipStream_t stream) {
    const float* x      = (const float*)d_in[0];
    const float* W_ih_f = (const float*)d_in[1];
    const float* W_hh_f = (const float*)d_in[2];
    const float* b_ih_f = (const float*)d_in[3];
    const float* b_hh_f = (const float*)d_in[4];
    const float* W_ih_b = (const float*)d_in[5];
    const float* W_hh_b = (const float*)d_in[6];
    const float* b_ih_b = (const float*)d_in[7];
    const float* b_hh_b = (const float*)d_in[8];
    const float* conv_w = (const float*)d_in[9];
    const float* conv_b = (const float*)d_in[10];

    // ws layout: [w12 8.4MB][w0 8.4MB][partial]
    const size_t wbytes = (size_t)NBLK * BATCH * 16;  // uint4 per (t4,b)
    const size_t pbytes1 = (size_t)NSEQ * HH * 4;     // per chunk
    size_t pbase = 2 * wbytes;
    int nchunk = 128;   // 4096 waves = 4/SIMD (r20-proven operating point)
    while (nchunk > 8 && ws_size < pbase + (size_t)nchunk * pbytes1)
        nchunk >>= 1;
    int bpc = NBLK / nchunk;

    uint4* w12 = (uint4*)d_ws;
    uint4* w0 = (uint4*)((char*)d_ws + wbytes);
    float* partial = (float*)((char*)d_ws + pbase);
    float* out = (float*)d_out;

    transpose_kernel<<<dim3(16 * 32), dim3(256), 0, stream>>>(
        (const float4*)x, w12, w0);
    rnn_kernel<<<dim3(32 * nchunk / 4), dim3(256), 0, stream>>>(
        w12, w0, W_ih_f, W_hh_f, b_ih_f, b_hh_f,
        W_ih_b, W_hh_b, b_ih_b, b_hh_b, partial, nchunk, bpc);
    finalize_kernel<<<dim3(BATCH), dim3(64), 0, stream>>>(
        partial, conv_w, conv_b, out, nchunk);
}

// Round 23
// 53.027 us; speedup vs baseline: 1.6607x; 1.1340x over previous
//
#include <hip/hip_runtime.h>
#include <hip/hip_fp16.h>

#define BATCH 512
#define NC 3
#define TT 4096
#define HH 17
#define NBLK (TT / 4)     // float4 time-blocks per sequence
#define WU_BLKS 3         // 12 warm-up steps
#define NSEQ (BATCH * 2)
#define SCALE 2.8853900817779268f   // 2*log2(e), folded into weights/bias

typedef __attribute__((ext_vector_type(8))) _Float16 half8;
typedef __attribute__((ext_vector_type(16))) float f32x16;

union H8 { unsigned u[4]; half8 s; };

__device__ __forceinline__ float fast_exp2(float y) {
#if __has_builtin(__builtin_amdgcn_exp2f)
    return __builtin_amdgcn_exp2f(y);   // bare v_exp_f32
#else
    return exp2f(y);
#endif
}

// tanh with 2*log2(e) pre-folded into the MFMA weights:
// d = 2*log2e*(Wh+Ux+b)  ->  tanh = 1 - 2/(2^d + 1).
__device__ __forceinline__ float fast_tanh_pre(float d) {
    float e = fast_exp2(d);
    float r = __builtin_amdgcn_rcpf(e + 1.0f);
    return fmaf(-2.0f, r, 1.0f);
}

// RNE fp16 helpers (default round mode; NOT pkrtz — RTZ biases the recurrence).
__device__ __forceinline__ unsigned h16u(float f) {
    return (unsigned)__half_as_ushort(__float2half(f));
}
__device__ __forceinline__ unsigned pk2h(float lo, float hi) {
    return h16u(lo) | (h16u(hi) << 16);
}

// x[B][C][T] -> prepacked fp16 B2-operand words, lane-contiguous in b:
//   w12[t4*BATCH+b] = uint4: fp16(x1)|fp16(x2)<<16 per t (4 t's)
//   w0 [t4*BATCH+b] = uint2: fp16(x0_t0)|fp16(x0_t1)<<16, fp16(x0_t2)|fp16(x0_t3)<<16
__global__ __launch_bounds__(256) void transpose_kernel(
    const float4* __restrict__ x4, uint4* __restrict__ w12,
    uint2* __restrict__ w0) {
    __shared__ float4 tile[NC][32][33];
    int bid = blockIdx.x;
    int tb = bid & 15;          // batch tile (16)
    int tt = bid >> 4;          // t4 tile (32)
    int b0 = tb * 32, t40 = tt * 32;
    int jr = threadIdx.x & 31, pr = threadIdx.x >> 5;
#pragma unroll
    for (int c = 0; c < NC; ++c)
#pragma unroll
        for (int p = 0; p < 4; ++p) {
            int r = p * 8 + pr;
            tile[c][r][jr] =
                x4[(size_t)(b0 + r) * (NC * NBLK) + c * NBLK + t40 + jr];
        }
    __syncthreads();
#pragma unroll
    for (int p = 0; p < 4; ++p) {
        int j = p * 8 + pr;
        int b = jr;
        float4 c0 = tile[0][b][j];
        float4 c1 = tile[1][b][j];
        float4 c2 = tile[2][b][j];
        uint4 a;
        a.x = pk2h(c1.x, c2.x);
        a.y = pk2h(c1.y, c2.y);
        a.z = pk2h(c1.z, c2.z);
        a.w = pk2h(c1.w, c2.w);
        uint2 z;
        z.x = pk2h(c0.x, c0.y);   // [15:0]=fp16(x0@t0) [31:16]=fp16(x0@t1)
        z.y = pk2h(c0.z, c0.w);   // t2, t3
        size_t idx = (size_t)(t40 + j) * BATCH + b0 + b;
        w12[idx] = a;
        w0[idx] = z;
    }
}

// Recurrence over one chunk — fp16 2-MFMA chain (r22-proven).
// D = s*[W_hh | W_hh[:,16], W_ih] x [h ; h16, x_t] + s*bias.
// D regs 0..7 of a lane ARE its next-step B fragment k-slots.
// The if(g) B2 masking is EMPIRICALLY REQUIRED (r8/r16 NaN) — keep.
template <int DIR>
__device__ __forceinline__ void run_loop(
    const uint4* __restrict__ p12, const uint2* __restrict__ p0,
    half8 A1, half8 A2,
    f32x16 Cb, int g, int blk0, int blkMain, int blkEnd, float* hs) {

    half8 Bhi = {0,0,0,0,0,0,0,0};
    unsigned h16b = 0;  // [15:0]=fp16(h16), rest 0

    int t4 = DIR ? (NBLK - 1 - blk0) : blk0;
    uint4 c12 = p12[(size_t)t4 * BATCH];
    uint2 c0 = p0[(size_t)t4 * BATCH];
    const int dstep = DIR ? -1 : 1;

    for (int blk = blk0; blk < blkEnd; ++blk) {
        int nt4 = (blk + 1 < blkEnd) ? t4 + dstep : t4;  // clamped prefetch
        uint4 n12 = p12[(size_t)nt4 * BATCH];
        uint2 n0 = p0[(size_t)nt4 * BATCH];

        const float flag = (blk >= blkMain) ? 1.0f : 0.0f;  // warm-up mask
        unsigned a12[4] = {c12.x, c12.y, c12.z, c12.w};
        unsigned a0w[2] = {c0.x, c0.y};

#pragma unroll
        for (int k = 0; k < 4; ++k) {
            const int kk = DIR ? (3 - k) : k;

            // x0 for step kk lives in half (kk&1) of word (kk>>1); place in hi16
            unsigned x0hi = (kk & 1) ? (a0w[kk >> 1] & 0xFFFF0000u)
                                     : (a0w[kk >> 1] << 16);
            // B2 = [h16, x0, x1, x2] fp16 (g==0 lanes live; mask REQUIRED)
            unsigned t0 = h16b | x0hi;
            unsigned t1 = a12[kk];
            if (g) { t0 = 0; t1 = 0; }
            H8 th; th.u[0] = t0; th.u[1] = t1; th.u[2] = 0; th.u[3] = 0;

            // two-MFMA chain (fp16 weights, fp16 data, fp32 accumulate)
            f32x16 D = __builtin_amdgcn_mfma_f32_32x32x16_f16(A1, Bhi, Cb, 0, 0, 0);
            D = __builtin_amdgcn_mfma_f32_32x32x16_f16(A2, th.s, D, 0, 0, 0);

            // tanh on live regs (rows <17 live in regs 0..8), accumulate sums
            float ht[9];
#pragma unroll
            for (int r = 0; r < 9; ++r) {
                ht[r] = fast_tanh_pre(D[r]);
                hs[r] = fmaf(ht[r], flag, hs[r]);
            }
            // next-step B fragment: regs 0..7 are exactly this lane's k-slots
            H8 nh;
            nh.u[0] = pk2h(ht[0], ht[1]);
            nh.u[1] = pk2h(ht[2], ht[3]);
            nh.u[2] = pk2h(ht[4], ht[5]);
            nh.u[3] = pk2h(ht[6], ht[7]);
            Bhi = nh.s;
            h16b = h16u(ht[8]);  // [15:0]=fp16(h16)
        }
        t4 = nt4;
        c12 = n12; c0 = n0;
    }
}

// 4 independent waves per 256-thread block (r15-proven geometry).
__global__ __launch_bounds__(256) void rnn_kernel(
    const uint4* __restrict__ w12, const uint2* __restrict__ w0,
    const float* __restrict__ W_ih_f, const float* __restrict__ W_hh_f,
    const float* __restrict__ b_ih_f, const float* __restrict__ b_hh_f,
    const float* __restrict__ W_ih_b, const float* __restrict__ W_hh_b,
    const float* __restrict__ b_ih_b, const float* __restrict__ b_hh_b,
    float* __restrict__ partial, int nchunk, int bpc) {
    int wv = threadIdx.x >> 6;          // wave within block
    int wid = blockIdx.x * 4 + wv;      // global wave id (nchunk%4==0 -> same q)
    int chunk = wid % nchunk;
    int q = wid / nchunk;
    int dir = q & 1;
    int grp = q >> 1;            // 0..15 (batch groups of 32)
    int lane = threadIdx.x & 63;
    int n = lane & 31;           // column = batch within group
    int g = lane >> 5;           // k-block / row-block selector
    int m = n;                   // A-operand row owned by this lane
    int bn = grp * 32 + n;

    const float* W_ih = dir ? W_ih_b : W_ih_f;
    const float* W_hh = dir ? W_hh_b : W_hh_f;
    const float* b_ih = dir ? b_ih_b : b_ih_f;
    const float* b_hh = dir ? b_hh_b : b_hh_f;

    // A fragments (fp16, RNE): rows m (pad >=17 with 0), k-slots {4g+i, 8+4g+i}
    // Weights pre-scaled by 2*log2e.
    half8 A1, A2;
#pragma unroll
    for (int i = 0; i < 8; ++i) {
        int k = (i < 4) ? (4 * g + i) : (8 + 4 * g + (i - 4));
        float wv_ = (m < HH && k < HH) ? W_hh[m * HH + k] * SCALE : 0.0f;
        A1[i] = (_Float16)wv_;
        // A2: k2-slots {16+4g+i, 24+4g+i}: k2==16 -> W_hh[:,16]; 17..19 -> W_ih
        int k2 = (i < 4) ? (16 + 4 * g + i) : (24 + 4 * g + (i - 4));
        float wv2 = 0.0f;
        if (m < HH) {
            if (k2 == 16) wv2 = W_hh[m * HH + 16] * SCALE;
            else if (k2 >= 17 && k2 <= 19) wv2 = W_ih[m * NC + (k2 - 17)] * SCALE;
        }
        A2[i] = (_Float16)wv2;
    }

    // C bias (pre-scaled): reg r holds row (r&3)+8*(r>>2)+4g; zero dead rows
    f32x16 Cb;
#pragma unroll
    for (int r = 0; r < 16; ++r) {
        int row = (r & 3) + 8 * (r >> 2) + 4 * g;
        Cb[r] = (row < HH) ? (b_ih[row] + b_hh[row]) * SCALE : 0.0f;
    }

    int blkMain = chunk * bpc;
    int blk0 = chunk ? (blkMain - WU_BLKS) : 0;
    int blkEnd = blkMain + bpc;

    const uint4* p12 = w12 + bn;
    const uint2* p0 = w0 + bn;

    float hs[9];
#pragma unroll
    for (int r = 0; r < 9; ++r) hs[r] = 0.0f;

    if (dir == 0)
        run_loop<0>(p12, p0, A1, A2, Cb, g, blk0, blkMain, blkEnd, hs);
    else
        run_loop<1>(p12, p0, A1, A2, Cb, g, blk0, blkMain, blkEnd, hs);

    // partial layout [chunk][seq][comp]: coalesced finalize reads
    int seq = bn * 2 + dir;
#pragma unroll
    for (int r = 0; r < 9; ++r) {
        int row = (r & 3) + 8 * (r >> 2) + 4 * g;
        if (row < HH)
            partial[(size_t)chunk * (NSEQ * HH) + seq * HH + row] = hs[r];
    }
}

// Fused reduce+conv: one 64-thread block per batch (r19-proven).
__global__ __launch_bounds__(64) void finalize_kernel(
    const float* __restrict__ partial, const float* __restrict__ conv_w,
    const float* __restrict__ conv_b, float* __restrict__ out, int nchunk) {
    int b = blockIdx.x;
    int lane = threadIdx.x;
    float tot = 0.0f;
    if (lane < 2 * HH) {
        const float* p = partial + (size_t)b * (2 * HH) + lane;
        float s0 = 0.0f, s1 = 0.0f, s2 = 0.0f, s3 = 0.0f;
        int c = 0;
        for (; c + 4 <= nchunk; c += 4) {
            s0 += p[(size_t)(c + 0) * (NSEQ * HH)];
            s1 += p[(size_t)(c + 1) * (NSEQ * HH)];
            s2 += p[(size_t)(c + 2) * (NSEQ * HH)];
            s3 += p[(size_t)(c + 3) * (NSEQ * HH)];
        }
        for (; c < nchunk; ++c) s0 += p[(size_t)c * (NSEQ * HH)];
        tot = (s0 + s1) + (s2 + s3);
    }
    float c0 = 0.0f, c1 = 0.0f;
    if (lane < 2 * HH) {
        c0 = conv_w[lane] * tot;            // conv_w[0][concat]
        c1 = conv_w[2 * HH + lane] * tot;   // conv_w[1][concat]
    }
#pragma unroll
    for (int off = 32; off; off >>= 1) {
        c0 += __shfl_down(c0, off);
        c1 += __shfl_down(c1, off);
    }
    if (lane == 0) {
        const float inv = 1.0f / (float)TT;
        out[b * 2 + 0] = fmaf(c0, inv, conv_b[0]);
        out[b * 2 + 1] = fmaf(c1, inv, conv_b[1]);
    }
}

extern "C" void kernel_launch(void* const* d_in, const int* in_sizes, int n_in,
                              void* d_out, int out_size, void* d_ws, size_t ws_size,
                              hipStream_t stream) {
    const float* x      = (const float*)d_in[0];
    const float* W_ih_f = (const float*)d_in[1];
    const float* W_hh_f = (const float*)d_in[2];
    const float* b_ih_f = (const float*)d_in[3];
    const float* b_hh_f = (const float*)d_in[4];
    const float* W_ih_b = (const float*)d_in[5];
    const float* W_hh_b = (const float*)d_in[6];
    const float* b_ih_b = (const float*)d_in[7];
    const float* b_hh_b = (const float*)d_in[8];
    const float* conv_w = (const float*)d_in[9];
    const float* conv_b = (const float*)d_in[10];

    // ws layout: [w12 8.4MB][w0 4.2MB][partial]
    const size_t w12bytes = (size_t)NBLK * BATCH * 16;  // uint4 per (t4,b)
    const size_t w0bytes = (size_t)NBLK * BATCH * 8;    // uint2 per (t4,b)
    const size_t pbytes1 = (size_t)NSEQ * HH * 4;       // per chunk
    size_t pbase = w12bytes + w0bytes;
    int nchunk = 64;   // 2048 waves = 2/SIMD; WU amortizes over 64 main steps
    while (nchunk > 8 && ws_size < pbase + (size_t)nchunk * pbytes1)
        nchunk >>= 1;
    int bpc = NBLK / nchunk;

    uint4* w12 = (uint4*)d_ws;
    uint2* w0 = (uint2*)((char*)d_ws + w12bytes);
    float* partial = (float*)((char*)d_ws + pbase);
    float* out = (float*)d_out;

    transpose_kernel<<<dim3(16 * 32), dim3(256), 0, stream>>>(
        (const float4*)x, w12, w0);
    rnn_kernel<<<dim3(32 * nchunk / 4), dim3(256), 0, stream>>>(
        w12, w0, W_ih_f, W_hh_f, b_ih_f, b_hh_f,
        W_ih_b, W_hh_b, b_ih_b, b_hh_b, partial, nchunk, bpc);
    finalize_kernel<<<dim3(BATCH), dim3(64), 0, stream>>>(
        partial, conv_w, conv_b, out, nchunk);
}